// Round 1
// baseline (145.668 us; speedup 1.0000x reference)
//
#include <hip/hip_runtime.h>

// Problem constants (match reference)
constexpr int B = 524288;
constexpr int L = 7;
constexpr int V = 40;
// Letter-slot masks: bit l set => position l must be a Letter
//   BRAZIL "LLLDDDD" -> positions 0,1,2        -> 0b0000111 = 0x07
//   MERC   "LLLDLDD" -> positions 0,1,2,4      -> 0b0010111 = 0x17
constexpr int BRAZIL_MASK = 0x07;
constexpr int MERC_MASK   = 0x17;

// Token id classes: 0..3 special, 4..29 letters, 30..39 digits.
// argmax is first-occurrence on ties, so group priority on exact ties is
// special > letter > digit (lower index wins).

__global__ __launch_bounds__(256) void layout_penalty_count(
    const float* __restrict__ logits,
    const int* __restrict__ is_merc,
    unsigned int* __restrict__ count)
{
    const int tid    = blockIdx.x * blockDim.x + threadIdx.x;
    const int stride = gridDim.x * blockDim.x;
    const int NROWS  = B * L;

    unsigned int local = 0;

    for (int r = tid; r < NROWS; r += stride) {
        const int b = r / 7;
        const int l = r - b * 7;
        const float4* row = reinterpret_cast<const float4*>(logits + (size_t)r * V);

        // block 0: ids 0..3 (special)
        float4 v0 = row[0];
        float m_sp = fmaxf(fmaxf(v0.x, v0.y), fmaxf(v0.z, v0.w));

        // blocks 1..6: ids 4..27 (letters)
        float m_le = -3.4e38f;
        #pragma unroll
        for (int k = 1; k <= 6; ++k) {
            float4 v = row[k];
            m_le = fmaxf(m_le, fmaxf(fmaxf(v.x, v.y), fmaxf(v.z, v.w)));
        }
        // block 7: ids 28,29 letters; 30,31 digits
        float4 v7 = row[7];
        m_le = fmaxf(m_le, fmaxf(v7.x, v7.y));
        float m_di = fmaxf(v7.z, v7.w);
        // blocks 8,9: ids 32..39 (digits)
        float4 v8 = row[8];
        float4 v9 = row[9];
        m_di = fmaxf(m_di, fmaxf(fmaxf(v8.x, v8.y), fmaxf(v8.z, v8.w)));
        m_di = fmaxf(m_di, fmaxf(fmaxf(v9.x, v9.y), fmaxf(v9.z, v9.w)));

        // Class of argmax with first-occurrence tie priority:
        //   digit wins only if strictly greater than both earlier groups;
        //   letter wins if strictly > special and >= digit.
        const bool pred_is_digit  = (m_di > m_sp) && (m_di > m_le);
        const bool pred_is_letter = (m_le > m_sp) && (m_le >= m_di);

        const int  mask  = (is_merc[b] > 0) ? MERC_MASK : BRAZIL_MASK;
        const bool lslot = (mask >> l) & 1;
        const bool viol  = lslot ? pred_is_digit : pred_is_letter;
        local += (unsigned int)viol;
    }

    // wave64 shuffle reduce
    #pragma unroll
    for (int off = 32; off > 0; off >>= 1)
        local += __shfl_down(local, off);

    __shared__ unsigned int s[4];  // 256 threads = 4 waves
    const int wid = threadIdx.x >> 6;
    if ((threadIdx.x & 63) == 0) s[wid] = local;
    __syncthreads();
    if (threadIdx.x == 0) {
        unsigned int t = s[0] + s[1] + s[2] + s[3];
        atomicAdd(count, t);
    }
}

__global__ void layout_penalty_finalize(const unsigned int* __restrict__ count,
                                        float* __restrict__ out)
{
    if (threadIdx.x == 0 && blockIdx.x == 0) {
        *out = 2.0f * (float)(*count) / (float)B;
    }
}

extern "C" void kernel_launch(void* const* d_in, const int* in_sizes, int n_in,
                              void* d_out, int out_size, void* d_ws, size_t ws_size,
                              hipStream_t stream) {
    const float* logits  = (const float*)d_in[0];
    const int*   is_merc = (const int*)d_in[1];
    float*       out     = (float*)d_out;
    unsigned int* count  = (unsigned int*)d_ws;

    hipMemsetAsync(count, 0, sizeof(unsigned int), stream);

    const int block = 256;
    const int grid  = 2048;  // grid-stride over B*L = 3,670,016 rows
    layout_penalty_count<<<grid, block, 0, stream>>>(logits, is_merc, count);
    layout_penalty_finalize<<<1, 64, 0, stream>>>(count, out);
}

// Round 2
// 105.220 us; speedup vs baseline: 1.3844x; 1.3844x over previous
//
#include <hip/hip_runtime.h>
#include <stdint.h>

// Problem constants (match reference)
constexpr int B = 524288;
constexpr int L = 7;
constexpr int V = 40;                       // 40 floats = 10 float4 per row
constexpr int NROWS = B * L;                // 3,670,016
constexpr int ROWS_PER_TILE = 256;          // one row per thread per tile
constexpr int F4_PER_ROW = 10;
constexpr int F4_PER_TILE = ROWS_PER_TILE * F4_PER_ROW;  // 2560 (40 KiB)
constexpr int NTILES = NROWS / ROWS_PER_TILE;            // 14336 (exact)
constexpr int GRID = 2048;                  // 14336 / 2048 = 7 tiles/block exact
// Letter-slot masks: bit l set => position l must be a Letter
constexpr int BRAZIL_MASK = 0x07;           // LLLDDDD
constexpr int MERC_MASK   = 0x17;           // LLLDLDD

// Token id classes: 0..3 special, 4..29 letters, 30..39 digits.
// argmax is first-occurrence: on exact ties special > letter > digit.

typedef __attribute__((address_space(3))) char lds_char;
typedef __attribute__((address_space(1))) char glob_char;

__global__ __launch_bounds__(256) void layout_penalty_count(
    const float* __restrict__ logits,
    const int* __restrict__ is_merc,
    unsigned int* __restrict__ block_counts)
{
    __shared__ float4 tile[F4_PER_TILE];    // exactly 40960 B -> 4 blocks/CU
    const int t = threadIdx.x;
    const int waveBase = t & ~63;           // wave-uniform

    unsigned int local = 0;

    for (int tileIdx = blockIdx.x; tileIdx < NTILES; tileIdx += GRID) {
        const size_t baseF4 = (size_t)tileIdx * F4_PER_TILE;

        // Stage 40 KiB: LDS layout linear == global order, so the
        // wave-uniform-dest + lane*16 rule of global_load_lds is satisfied.
        #pragma unroll
        for (int j = 0; j < F4_PER_ROW; ++j) {
            const float4* gp = reinterpret_cast<const float4*>(logits)
                               + baseF4 + (size_t)(j * 256 + t);
            lds_char* lp = (lds_char*)((char*)tile + (size_t)(j * 256 + waveBase) * 16);
            __builtin_amdgcn_global_load_lds((const glob_char*)gp, lp, 16, 0, 0);
        }
        __syncthreads();   // compiler drains vmcnt before the barrier

        // Thread t owns row t of the tile.
        const float4* row = &tile[t * F4_PER_ROW];

        float4 v0 = row[0];                 // ids 0..3 special
        float m_sp = fmaxf(fmaxf(v0.x, v0.y), fmaxf(v0.z, v0.w));

        float m_le = -3.4e38f;              // ids 4..27
        #pragma unroll
        for (int k = 1; k <= 6; ++k) {
            float4 v = row[k];
            m_le = fmaxf(m_le, fmaxf(fmaxf(v.x, v.y), fmaxf(v.z, v.w)));
        }
        float4 v7 = row[7];                 // 28,29 letters; 30,31 digits
        m_le = fmaxf(m_le, fmaxf(v7.x, v7.y));
        float m_di = fmaxf(v7.z, v7.w);
        float4 v8 = row[8];
        float4 v9 = row[9];
        m_di = fmaxf(m_di, fmaxf(fmaxf(v8.x, v8.y), fmaxf(v8.z, v8.w)));
        m_di = fmaxf(m_di, fmaxf(fmaxf(v9.x, v9.y), fmaxf(v9.z, v9.w)));

        const bool pred_is_digit  = (m_di > m_sp) && (m_di > m_le);
        const bool pred_is_letter = (m_le > m_sp) && (m_le >= m_di);

        const int R = tileIdx * ROWS_PER_TILE + t;
        const int b = R / 7;
        const int l = R - b * 7;
        const int  mask  = (is_merc[b] > 0) ? MERC_MASK : BRAZIL_MASK;
        const bool lslot = (mask >> l) & 1;
        local += (unsigned int)(lslot ? pred_is_digit : pred_is_letter);

        __syncthreads();   // all reads done before next tile overwrites LDS
    }

    // Block reduction: wave shfl, then reuse tile LDS (all tile reads done).
    #pragma unroll
    for (int off = 32; off > 0; off >>= 1)
        local += __shfl_down(local, off);

    unsigned int* s = reinterpret_cast<unsigned int*>(tile);
    const int wid = t >> 6;
    if ((t & 63) == 0) s[wid] = local;
    __syncthreads();
    if (t == 0)
        block_counts[blockIdx.x] = s[0] + s[1] + s[2] + s[3];
}

__global__ __launch_bounds__(256) void layout_penalty_finalize(
    const unsigned int* __restrict__ block_counts,
    float* __restrict__ out)
{
    unsigned int local = 0;
    for (int i = threadIdx.x; i < GRID; i += 256)
        local += block_counts[i];
    #pragma unroll
    for (int off = 32; off > 0; off >>= 1)
        local += __shfl_down(local, off);

    __shared__ unsigned int s[4];
    const int wid = threadIdx.x >> 6;
    if ((threadIdx.x & 63) == 0) s[wid] = local;
    __syncthreads();
    if (threadIdx.x == 0)
        *out = 2.0f * (float)(s[0] + s[1] + s[2] + s[3]) / (float)B;
}

extern "C" void kernel_launch(void* const* d_in, const int* in_sizes, int n_in,
                              void* d_out, int out_size, void* d_ws, size_t ws_size,
                              hipStream_t stream) {
    const float* logits  = (const float*)d_in[0];
    const int*   is_merc = (const int*)d_in[1];
    float*       out     = (float*)d_out;
    unsigned int* block_counts = (unsigned int*)d_ws;   // GRID entries, fully rewritten each call

    layout_penalty_count<<<GRID, 256, 0, stream>>>(logits, is_merc, block_counts);
    layout_penalty_finalize<<<1, 256, 0, stream>>>(block_counts, out);
}